// Round 4
// baseline (471.604 us; speedup 1.0000x reference)
//
#include <hip/hip_runtime.h>

// SoftmaxRBM fused single-kernel: prob = softmax_groups16( hidden @ W^T + a ).
// M=NVIS=65536, N=POP=1024, K=NH=256.
//
// v3 vs v2 (175 us, MfmaUtil 7.7, occ 20%, FETCH 4x W):
//  1. XCD-group swizzle: all 16 panel-blocks of one m-slice on ONE XCD
//     (id%8 == mblk%8 under %8 round-robin) -> W slice fetched once per L2,
//     frag loads become L2-hits (~200cyc) instead of L3/HBM (~900cyc).
//  2. Occupancy 8 -> 12 waves/CU: wave tile 64x64 (acc[4][4]=64 regs),
//     BN=64 (LDS 32 KB), launch_bounds(256,3). (Not 4/SIMD: that needs
//     <=128 total regs incl. accumulator -> spill risk.)
//  3. LDS in MFMA-frag order [j][nt][lane][8]: B-frag ds_read_b128 is
//     lane-linear (base + lane*16B) -> bank-conflict-free (v2: 3.1M cycles).
// Kept from v2: terminal stores (vmcnt shared by loads+stores retires in
// issue order -> stores must come last), split epilogue (all bias loads
// before any store), non-temporal output stores, 1-deep W prefetch,
// barrier-free K-loop, in-register fp32->bf16 truncation (same numerics).

typedef short  bf16x8 __attribute__((ext_vector_type(8)));
typedef float  f32x4  __attribute__((ext_vector_type(4)));

#define NH    256
#define POP   1024
#define NVIS  65536
#define BN    64      // batch cols per block (POP/BN = 16 panels)
#define MBLK  256     // visible rows per block = 4 waves x 64
#define NT    4       // BN/16 MFMA n-tiles

__device__ __forceinline__ unsigned pack2bf(float lo, float hi) {
  return (__float_as_uint(hi) & 0xffff0000u) | (__float_as_uint(lo) >> 16);
}

__global__ __launch_bounds__(256, 3) void rbm_fused_kernel(
    const float* __restrict__ Hg,  // [POP][NH]   fp32
    const float* __restrict__ Wg,  // [NVIS][NH]  fp32
    const float* __restrict__ Ag,  // [NVIS]      fp32
    float* __restrict__ out)       // [POP][NVIS] fp32
{
  // H panel in MFMA-frag order: [j][nt][lane][8] bf16 = 32 KB.
  // slot(j,nt,lane) = H[n_base + nt*16 + (lane&15)][j*32 + (lane>>4)*8 .. +8]
  __shared__ short sB[8 * NT * 64 * 8];

  const int tid  = threadIdx.x;
  const int lane = tid & 63;
  const int wave = tid >> 6;
  const int quad = lane >> 4;
  const int col  = lane & 15;

  // XCD-grouping swizzle (bijective): id%8 selects XCD (round-robin model);
  // mblk%8 == id%8 so the 16 panel-blocks of one mblk share one XCD's L2.
  const int id    = blockIdx.x;
  const int xcd   = id & 7;
  const int qq    = id >> 3;             // 0..511
  const int mblk  = xcd + 8 * (qq >> 4); // 0..255, mblk%8 == xcd
  const int panel = qq & 15;             // 0..15
  const int n_base = panel * BN;
  const int m0     = mblk * MBLK + wave * 64;   // this wave's 64 v-rows

  // ---- stage H panel fp32 -> bf16 into frag-order LDS (once, 1 barrier)
  {
    const int r   = tid >> 2;            // 0..63: H row within panel
    const int sub = tid & 3;             // k-quad within 32-k slice
    const float* src = Hg + (size_t)(n_base + r) * NH + sub * 8;
    short* dst = &sB[((r >> 4) * 64 + sub * 16 + (r & 15)) * 8];
    #pragma unroll
    for (int j = 0; j < 8; ++j) {
      const float4 f0 = ((const float4*)(src + j * 32))[0];
      const float4 f1 = ((const float4*)(src + j * 32))[1];
      uint4 u;
      u.x = pack2bf(f0.x, f0.y); u.y = pack2bf(f0.z, f0.w);
      u.z = pack2bf(f1.x, f1.y); u.w = pack2bf(f1.z, f1.w);
      *(uint4*)(dst + j * (NT * 64 * 8)) = u;
    }
  }
  __syncthreads();   // the ONLY barrier in the kernel

  f32x4 acc[4][NT];
  #pragma unroll
  for (int mt = 0; mt < 4; ++mt)
    #pragma unroll
    for (int nt = 0; nt < NT; ++nt)
      acc[mt][nt] = f32x4{0.f, 0.f, 0.f, 0.f};

  // A-frag: lane reads W[m0 + mt*16 + col][j*32 + quad*8 .. +8] (fp32).
  const float* abase = Wg + (size_t)(m0 + col) * NH + quad * 8;

  // prefetch j=0
  float4 pf[4][2];
  #pragma unroll
  for (int mt = 0; mt < 4; ++mt) {
    const float4* p = (const float4*)(abase + (size_t)mt * 16 * NH);
    pf[mt][0] = p[0];
    pf[mt][1] = p[1];
  }

  #pragma unroll
  for (int j = 0; j < 8; ++j) {
    // pack current fp32 frags -> bf16 (truncation, same numerics as before)
    bf16x8 af[4];
    #pragma unroll
    for (int mt = 0; mt < 4; ++mt) {
      union { bf16x8 v; uint4 u; } cv;
      cv.u.x = pack2bf(pf[mt][0].x, pf[mt][0].y);
      cv.u.y = pack2bf(pf[mt][0].z, pf[mt][0].w);
      cv.u.z = pack2bf(pf[mt][1].x, pf[mt][1].y);
      cv.u.w = pack2bf(pf[mt][1].z, pf[mt][1].w);
      af[mt] = cv.v;
    }
    // issue next-j W loads (no stores outstanding -> precise vmcnt waits)
    if (j < 7) {
      #pragma unroll
      for (int mt = 0; mt < 4; ++mt) {
        const float4* p =
            (const float4*)(abase + (size_t)mt * 16 * NH + (j + 1) * 32);
        pf[mt][0] = p[0];
        pf[mt][1] = p[1];
      }
    }
    // B frags: lane-linear conflict-free ds_read_b128 + MFMA cluster
    const short* bb = &sB[j * (NT * 64 * 8) + lane * 8];
    #pragma unroll
    for (int nt = 0; nt < NT; ++nt) {
      const bf16x8 bf = *(const bf16x8*)(bb + nt * (64 * 8));
      #pragma unroll
      for (int mt = 0; mt < 4; ++mt)
        acc[mt][nt] = __builtin_amdgcn_mfma_f32_16x16x32_bf16(
            af[mt], bf, acc[mt][nt], 0, 0, 0);
    }
  }

  // ---- epilogue phase A: bias + segmented softmax, written back into acc.
  // All loads (Ag) precede ALL stores -> no load waits behind a store.
  // C/D layout: col(n)=lane&15, row(m)=quad*4+reg -> lane holds 4 consec v.
  #pragma unroll
  for (int mt = 0; mt < 4; ++mt) {
    const int v0 = m0 + mt * 16 + quad * 4;
    const float4 av = *(const float4*)(Ag + v0);
    #pragma unroll
    for (int nt = 0; nt < NT; ++nt) {
      f32x4 c = acc[mt][nt];
      float x0 = c[0] + av.x, x1 = c[1] + av.y;
      float x2 = c[2] + av.z, x3 = c[3] + av.w;
      float mx = fmaxf(fmaxf(x0, x1), fmaxf(x2, x3));
      mx = fmaxf(mx, __shfl_xor(mx, 16));
      mx = fmaxf(mx, __shfl_xor(mx, 32));
      float e0 = __expf(x0 - mx), e1 = __expf(x1 - mx);
      float e2 = __expf(x2 - mx), e3 = __expf(x3 - mx);
      float s = (e0 + e1) + (e2 + e3);
      s += __shfl_xor(s, 16);
      s += __shfl_xor(s, 32);
      const float inv = 1.0f / s;
      f32x4 o;
      o[0] = e0 * inv; o[1] = e1 * inv; o[2] = e2 * inv; o[3] = e3 * inv;
      acc[mt][nt] = o;
    }
  }

  // ---- epilogue phase B: terminal non-temporal stores; wave retires after.
  #pragma unroll
  for (int mt = 0; mt < 4; ++mt) {
    const int v0 = m0 + mt * 16 + quad * 4;
    #pragma unroll
    for (int nt = 0; nt < NT; ++nt) {
      const int b = n_base + nt * 16 + col;
      // non-temporal: don't let 268 MB of streaming writes evict W from L2/L3.
      __builtin_nontemporal_store(acc[mt][nt],
                                  (f32x4*)(out + (size_t)b * NVIS + v0));
    }
  }
}

extern "C" void kernel_launch(void* const* d_in, const int* in_sizes, int n_in,
                              void* d_out, int out_size, void* d_ws, size_t ws_size,
                              hipStream_t stream) {
  const float* hidden = (const float*)d_in[0]; // [1024][256]
  const float* W      = (const float*)d_in[1]; // [65536][256]
  const float* a      = (const float*)d_in[2]; // [65536]
  float* out          = (float*)d_out;         // [1024][65536]
  (void)d_ws; (void)ws_size;

  const int nblocks = (POP / BN) * (NVIS / MBLK);  // 16 * 256 = 4096
  rbm_fused_kernel<<<nblocks, 256, 0, stream>>>(hidden, W, a, out);
}